// Round 1
// baseline (80.861 us; speedup 1.0000x reference)
//
#include <hip/hip_runtime.h>
#include <cstddef>

#define B_ 32
#define N_ 128
#define D_ 128
#define NEG_SLOPE 0.01f

// Kernel A: scores + leakyrelu + softmax -> alphas [B, N, N]
// One block per (b, i); 128 threads, one per j.
__global__ void attn_scores_kernel(const float* __restrict__ e,
                                   const float* __restrict__ w,
                                   const float* __restrict__ bias,
                                   float* __restrict__ alphas) {
    const int bi = blockIdx.x;          // 0 .. B*N-1
    const int b  = bi >> 7;             // /128
    const int i  = bi & 127;
    const int j  = threadIdx.x;         // 0..127

    __shared__ float h[D_];             // e[b,i,:] * w[:]
    __shared__ float red[N_];

    const float* ei = e + ((size_t)b * N_ + i) * D_;
    h[j] = ei[j] * w[j];
    __syncthreads();

    const float* ej = e + ((size_t)b * N_ + j) * D_;
    float s = 0.f;
#pragma unroll
    for (int d = 0; d < D_; d += 4) {
        const float4 hv = *reinterpret_cast<const float4*>(&h[d]);
        const float4 ev = *reinterpret_cast<const float4*>(&ej[d]);
        s += hv.x * ev.x + hv.y * ev.y + hv.z * ev.z + hv.w * ev.w;
    }
    s += bias[0];
    s = (s >= 0.f) ? s : NEG_SLOPE * s;

    // row max
    red[j] = s;
    __syncthreads();
#pragma unroll
    for (int off = 64; off > 0; off >>= 1) {
        if (j < off) red[j] = fmaxf(red[j], red[j + off]);
        __syncthreads();
    }
    const float m = red[0];
    __syncthreads();

    const float ex = expf(s - m);
    red[j] = ex;
    __syncthreads();
#pragma unroll
    for (int off = 64; off > 0; off >>= 1) {
        if (j < off) red[j] += red[j + off];
        __syncthreads();
    }
    const float denom = red[0];

    alphas[(size_t)bi * N_ + j] = ex / denom;
}

// Kernel B: value[b,i,j,d] = e[b,i,d] * e[b,j,d], float4-vectorized.
// One thread per 16B chunk; exact grid.
__global__ void value_kernel(const float* __restrict__ e,
                             float* __restrict__ value) {
    const size_t idx = (size_t)blockIdx.x * blockDim.x + threadIdx.x;
    // idx in [0, B*N*N*D/4) = 16,777,216
    const int d4 = (int)(idx & 31);          // D/4 = 32
    const int j  = (int)((idx >> 5) & 127);
    const int i  = (int)((idx >> 12) & 127);
    const int b  = (int)(idx >> 19);

    const float4 ei = *reinterpret_cast<const float4*>(
        e + ((size_t)b * N_ + i) * D_ + (d4 << 2));
    const float4 ej = *reinterpret_cast<const float4*>(
        e + ((size_t)b * N_ + j) * D_ + (d4 << 2));

    float4 v;
    v.x = ei.x * ej.x;
    v.y = ei.y * ej.y;
    v.z = ei.z * ej.z;
    v.w = ei.w * ej.w;

    reinterpret_cast<float4*>(value)[idx] = v;
}

extern "C" void kernel_launch(void* const* d_in, const int* in_sizes, int n_in,
                              void* d_out, int out_size, void* d_ws, size_t ws_size,
                              hipStream_t stream) {
    const float* e    = (const float*)d_in[0];   // [B, N, D]
    const float* w    = (const float*)d_in[1];   // [D]
    const float* bias = (const float*)d_in[2];   // [1]

    float* out    = (float*)d_out;
    float* alphas = out;                              // B*N*N
    float* value  = out + (size_t)B_ * N_ * N_;       // B*N*N*D

    attn_scores_kernel<<<B_ * N_, N_, 0, stream>>>(e, w, bias, alphas);

    const size_t total4 = (size_t)B_ * N_ * N_ * D_ / 4;  // 16,777,216
    const int block = 256;
    const int grid = (int)(total4 / block);               // 65,536
    value_kernel<<<grid, block, 0, stream>>>(e, value);
}

// Round 2
// 49.725 us; speedup vs baseline: 1.6262x; 1.6262x over previous
//
#include <hip/hip_runtime.h>
#include <cstddef>

#define B_ 32
#define N_ 128
#define D_ 128
#define NEG_SLOPE 0.01f

// Fused: value[b,i,j,d] = e[b,i,d]*e[b,j,d]  (256 MB stream write)
//        scores[b,i,j]  = sum_d value*w + bias -> leakyrelu -> softmax_j -> alphas
// One block per (b,i): 256 threads, t -> (d4 = t&31, jg = t>>5).
// 16 iterations over j = jj*8 + jg. Score dot reuses the v4 already computed.
__global__ void __launch_bounds__(256)
fused_value_attn_kernel(const float* __restrict__ e,
                        const float* __restrict__ w,
                        const float* __restrict__ bias,
                        float* __restrict__ alphas,
                        float* __restrict__ value) {
    const int bi = blockIdx.x;          // b*N + i
    const int b  = bi >> 7;
    const int t  = threadIdx.x;
    const int d4 = t & 31;              // which float4 of the D=128 row
    const int jg = t >> 5;              // 0..7

    __shared__ float sc[N_];
    __shared__ float red[N_];

    // Loop-invariant registers
    const float4 w4  = *reinterpret_cast<const float4*>(w + (d4 << 2));
    const float4 ei4 = *reinterpret_cast<const float4*>(
        e + (size_t)bi * D_ + (d4 << 2));
    const float bias0 = bias[0];

    // value row base for this block: value[bi*N*D ...]
    float4* __restrict__ vout = reinterpret_cast<float4*>(
        value + (size_t)bi * N_ * D_);

#pragma unroll 4
    for (int jj = 0; jj < 16; ++jj) {
        const int j = (jj << 3) + jg;   // 0..127
        const float4 ej4 = *reinterpret_cast<const float4*>(
            e + ((size_t)((b << 7) | j)) * D_ + (d4 << 2));

        float4 v4;
        v4.x = ei4.x * ej4.x;
        v4.y = ei4.y * ej4.y;
        v4.z = ei4.z * ej4.z;
        v4.w = ei4.w * ej4.w;

        vout[(j << 5) + d4] = v4;       // (j*D + d4*4)/4

        // partial score: sum_d v[d]*w[d] over this thread's 4 d's
        float p = v4.x * w4.x + v4.y * w4.y + v4.z * w4.z + v4.w * w4.w;
        // butterfly over the 32 lanes sharing this j (masks stay within 32-group)
        p += __shfl_xor(p, 1);
        p += __shfl_xor(p, 2);
        p += __shfl_xor(p, 4);
        p += __shfl_xor(p, 8);
        p += __shfl_xor(p, 16);
        if (d4 == 0) sc[j] = p;
    }
    __syncthreads();

    // Softmax over j (threads 0..127 own one j each; all threads hit barriers)
    float s = 0.f, ex = 0.f;
    if (t < N_) {
        s = sc[t] + bias0;
        s = (s >= 0.f) ? s : NEG_SLOPE * s;
        red[t] = s;
    }
    __syncthreads();
#pragma unroll
    for (int off = 64; off > 0; off >>= 1) {
        if (t < off) red[t] = fmaxf(red[t], red[t + off]);
        __syncthreads();
    }
    const float m = red[0];
    __syncthreads();
    if (t < N_) { ex = expf(s - m); red[t] = ex; }
    __syncthreads();
#pragma unroll
    for (int off = 64; off > 0; off >>= 1) {
        if (t < off) red[t] += red[t + off];
        __syncthreads();
    }
    if (t < N_) alphas[(size_t)bi * N_ + t] = ex / red[0];
}

extern "C" void kernel_launch(void* const* d_in, const int* in_sizes, int n_in,
                              void* d_out, int out_size, void* d_ws, size_t ws_size,
                              hipStream_t stream) {
    const float* e    = (const float*)d_in[0];   // [B, N, D]
    const float* w    = (const float*)d_in[1];   // [D]
    const float* bias = (const float*)d_in[2];   // [1]

    float* out    = (float*)d_out;
    float* alphas = out;                              // B*N*N
    float* value  = out + (size_t)B_ * N_ * N_;       // B*N*N*D

    fused_value_attn_kernel<<<B_ * N_, 256, 0, stream>>>(e, w, bias, alphas, value);
}